// Round 5
// baseline (882.424 us; speedup 1.0000x reference)
//
#include <hip/hip_runtime.h>
#include <math.h>

#define NEG_SLOPE 0.05f

__device__ __forceinline__ float leaky(float x){ return x >= 0.f ? x : NEG_SLOPE * x; }

// bf16 helpers (RNE pack, truncated-float unpack)
__device__ __forceinline__ unsigned short f2bf(float f){
    unsigned u = __float_as_uint(f);
    unsigned r = u + 0x7FFFu + ((u >> 16) & 1u);
    return (unsigned short)(r >> 16);
}
__device__ __forceinline__ float bf2f(unsigned short us){
    return __uint_as_float((unsigned)us << 16);
}

// ---------------- K0: zero degree arrays ----------------
__global__ __launch_bounds__(256) void k_init(int* deg_n, int* deg_o, int N){
    int t = blockIdx.x * blockDim.x + threadIdx.x;
    int stride = gridDim.x * blockDim.x;
    for (int i = t; i < N; i += stride){ deg_n[i] = 0; deg_o[i] = 0; }
}

// ---------------- tiled GEMM: C[M x 64] = A[M x K] @ B[64 x K]^T (+ optional bf16 copy) ----------------
template<int K, bool LEAKY, bool BF16OUT>
__global__ __launch_bounds__(256) void k_gemm64(const float* __restrict__ A, const float* __restrict__ B,
                                                float* __restrict__ C, unsigned short* __restrict__ Cb,
                                                int M, int ldC){
    __shared__ float As[K][68];
    __shared__ float Bs[K][68];
    const int m0 = blockIdx.x * 64;
    const int t = threadIdx.x;
    for (int i = t; i < 16 * K; i += 256){
        int d = i & 63, kq = i >> 6;
        float4 b = *(const float4*)&B[(size_t)d * K + kq * 4];
        Bs[kq*4+0][d] = b.x; Bs[kq*4+1][d] = b.y; Bs[kq*4+2][d] = b.z; Bs[kq*4+3][d] = b.w;
    }
    for (int i = t; i < 16 * K; i += 256){
        int r = i & 63, kq = i >> 6;
        int m = m0 + r;
        float4 a = make_float4(0.f, 0.f, 0.f, 0.f);
        if (m < M) a = *(const float4*)&A[(size_t)m * K + kq * 4];
        As[kq*4+0][r] = a.x; As[kq*4+1][r] = a.y; As[kq*4+2][r] = a.z; As[kq*4+3][r] = a.w;
    }
    __syncthreads();
    const int tx = t & 15, ty = t >> 4;
    float acc[4][4] = {};
    #pragma unroll 4
    for (int k = 0; k < K; k++){
        float4 a4 = *(const float4*)&As[k][ty * 4];
        float4 b4 = *(const float4*)&Bs[k][tx * 4];
        float av[4] = {a4.x, a4.y, a4.z, a4.w};
        float bv[4] = {b4.x, b4.y, b4.z, b4.w};
        #pragma unroll
        for (int r = 0; r < 4; r++)
            #pragma unroll
            for (int c = 0; c < 4; c++)
                acc[r][c] = fmaf(av[r], bv[c], acc[r][c]);
    }
    #pragma unroll
    for (int r = 0; r < 4; r++){
        int m = m0 + ty * 4 + r;
        if (m < M){
            float4 o;
            o.x = LEAKY ? leaky(acc[r][0]) : acc[r][0];
            o.y = LEAKY ? leaky(acc[r][1]) : acc[r][1];
            o.z = LEAKY ? leaky(acc[r][2]) : acc[r][2];
            o.w = LEAKY ? leaky(acc[r][3]) : acc[r][3];
            *(float4*)&C[(size_t)m * ldC + tx * 4] = o;
            if (BF16OUT){
                uint2 u;
                u.x = (unsigned)f2bf(o.x) | ((unsigned)f2bf(o.y) << 16);
                u.y = (unsigned)f2bf(o.z) | ((unsigned)f2bf(o.w) << 16);
                *(uint2*)&Cb[(size_t)m * 64 + tx * 4] = u;
            }
        }
    }
}

// ---------------- per-node scalars hi/hj/he ----------------
__global__ __launch_bounds__(256) void k_scal(const float* __restrict__ h,
        const float* __restrict__ a_node, const float* __restrict__ a_edge,
        float* __restrict__ hi, float* __restrict__ hj, float* __restrict__ he, int N){
    int i = blockIdx.x * 256 + threadIdx.x;
    if (i >= N) return;
    const float4* hr = (const float4*)(h + (size_t)i * 64);
    const float4* a1 = (const float4*)a_node;
    const float4* a2 = (const float4*)(a_node + 64);
    const float4* a3 = (const float4*)a_edge;
    float s1 = 0.f, s2 = 0.f, s3 = 0.f;
    #pragma unroll
    for (int q = 0; q < 16; q++){
        float4 v = hr[q], w1 = a1[q], w2 = a2[q], w3 = a3[q];
        s1 += v.x*w1.x + v.y*w1.y + v.z*w1.z + v.w*w1.w;
        s2 += v.x*w2.x + v.y*w2.y + v.z*w2.z + v.w*w2.w;
        s3 += v.x*w3.x + v.y*w3.y + v.z*w3.z + v.w*w3.w;
    }
    hi[i] = s1; hj[i] = s2; he[i] = s3;
}

// ---------------- ge[k] = ea[k].(We^T a2); also emit bf16 copy of ea ----------------
__global__ __launch_bounds__(256) void k_ge(const float* __restrict__ ea,
        const float* __restrict__ We, const float* __restrict__ a_edge,
        float* __restrict__ ge, unsigned short* __restrict__ eab, int E){
    __shared__ float v[64];
    if (threadIdx.x < 64){
        float s = 0.f;
        for (int d = 0; d < 64; d++) s = fmaf(We[d * 64 + threadIdx.x], a_edge[64 + d], s);
        v[threadIdx.x] = s;
    }
    __syncthreads();
    int k = blockIdx.x * 256 + threadIdx.x;
    if (k >= E) return;
    const float4* row = (const float4*)(ea + (size_t)k * 64);
    uint2* brow = (uint2*)(eab + (size_t)k * 64);
    float s = 0.f;
    #pragma unroll
    for (int q = 0; q < 16; q++){
        float4 r = row[q];
        s = fmaf(r.x, v[4*q+0], s);
        s = fmaf(r.y, v[4*q+1], s);
        s = fmaf(r.z, v[4*q+2], s);
        s = fmaf(r.w, v[4*q+3], s);
        uint2 u;
        u.x = (unsigned)f2bf(r.x) | ((unsigned)f2bf(r.y) << 16);
        u.y = (unsigned)f2bf(r.z) | ((unsigned)f2bf(r.w) << 16);
        brow[q] = u;
    }
    ge[k] = s;
}

// ---------------- XCD-partitioned degree count (2 atomics/edge) ----------------
__global__ __launch_bounds__(256) void k_count(const int* __restrict__ idx,
        int* __restrict__ deg_n, int* __restrict__ deg_o, int E, int N){
    int g = blockIdx.x & 7;
    int lo = (int)(((long long)g * N) >> 3), hi = (int)(((long long)(g + 1) * N) >> 3);
    int nblk = gridDim.x >> 3;
    int start = ((blockIdx.x >> 3) * 256) + threadIdx.x;
    int stride = nblk * 256;
    for (int k = start; k < E; k += stride){
        int i0 = idx[k], i1 = idx[E + k];
        if (i0 >= lo && i0 < hi) atomicAdd(&deg_n[i0], 1);
        if (i1 >= lo && i1 < hi) atomicAdd(&deg_o[i1], 1);
    }
}

// ---------------- chunked shfl scan; block1 also materializes deg_e ----------------
__global__ __launch_bounds__(1024) void k_scan(const int* __restrict__ deg_n, const int* __restrict__ deg_o,
                                               int* __restrict__ off_n, int* __restrict__ cur_n,
                                               int* __restrict__ off_e, int* __restrict__ cur_e,
                                               int* __restrict__ deg_e, int N){
    const bool eb = blockIdx.x != 0;
    int* off = eb ? off_e : off_n;
    int* cur = eb ? cur_e : cur_n;
    const int t = threadIdx.x;
    const int C = (N + 1023) / 1024;
    int base = t * C;
    int lim = min(C, N - base); if (lim < 0) lim = 0;
    int s = 0;
    for (int j = 0; j < lim; j++){
        int d = deg_n[base + j];
        if (eb) d += deg_o[base + j];
        s += d;
    }
    int lane = t & 63, w = t >> 6;
    int v = s;
    #pragma unroll
    for (int d = 1; d < 64; d <<= 1){ int o = __shfl_up(v, d); if (lane >= d) v += o; }
    __shared__ int wt[16];
    if (lane == 63) wt[w] = v;
    __syncthreads();
    if (w == 0 && lane < 16){
        int z = wt[lane];
        #pragma unroll
        for (int d = 1; d < 16; d <<= 1){ int o = __shfl_up(z, d); if (lane >= d) z += o; }
        wt[lane] = z;
    }
    __syncthreads();
    int run = (w ? wt[w - 1] : 0) + v - s;
    for (int j = 0; j < lim; j++){
        int d = deg_n[base + j];
        if (eb){ d += deg_o[base + j]; deg_e[base + j] = d; }
        off[base + j] = run; cur[base + j] = run;
        run += d;
    }
}

// ---------------- XCD-partitioned fill; records carry the attention scalar ----------------
__global__ __launch_bounds__(256) void k_fill(const int* __restrict__ idx,
        const float* __restrict__ hj, const float* __restrict__ ge,
        int* __restrict__ cur_n, int* __restrict__ cur_e,
        int2* __restrict__ adj_n, int2* __restrict__ adj_e, int E, int N){
    int g = blockIdx.x & 7;
    int lo = (int)(((long long)g * N) >> 3), hi = (int)(((long long)(g + 1) * N) >> 3);
    int nblk = gridDim.x >> 3;
    int start = ((blockIdx.x >> 3) * 256) + threadIdx.x;
    int stride = nblk * 256;
    for (int k = start; k < E; k += stride){
        int i0 = idx[k], i1 = idx[E + k];
        bool t0 = (i0 >= lo && i0 < hi), t1 = (i1 >= lo && i1 < hi);
        if (t0 | t1){
            int gb = __float_as_int(ge[k]);
            if (t0){
                adj_n[atomicAdd(&cur_n[i0], 1)] = make_int2(i1, __float_as_int(hj[i1]));
                adj_e[atomicAdd(&cur_e[i0], 1)] = make_int2(k, gb);
            }
            if (t1) adj_e[atomicAdd(&cur_e[i1], 1)] = make_int2(k, gb);
        }
    }
}

// ---------------- node branch: out[:, :64] (direct exp, bf16 gathers) ----------------
__global__ __launch_bounds__(256) void k_out_n(const float* __restrict__ h,
        const unsigned short* __restrict__ hb,
        const float* __restrict__ hi, const float* __restrict__ hj,
        const int* __restrict__ off_n, const int* __restrict__ deg_n,
        const int2* __restrict__ adj_n,
        float* __restrict__ out, int N){
    int lane = threadIdx.x & 63;
    int i = (blockIdx.x * 256 + threadIdx.x) >> 6;
    if (i >= N) return;
    float hi_i = hi[i];
    float wself = __expf(leaky(hi_i + hj[i]));
    float s = wself;
    float acc = wself * h[(size_t)i * 64 + lane];
    int cnt = deg_n[i];
    int p = off_n[i], e = p + cnt;
    for (; p + 4 <= e; p += 4){
        int2 r0 = adj_n[p], r1 = adj_n[p+1], r2 = adj_n[p+2], r3 = adj_n[p+3];
        float v0 = bf2f(hb[(size_t)r0.x * 64 + lane]);
        float v1 = bf2f(hb[(size_t)r1.x * 64 + lane]);
        float v2 = bf2f(hb[(size_t)r2.x * 64 + lane]);
        float v3 = bf2f(hb[(size_t)r3.x * 64 + lane]);
        float w0 = __expf(leaky(hi_i + __int_as_float(r0.y)));
        float w1 = __expf(leaky(hi_i + __int_as_float(r1.y)));
        float w2 = __expf(leaky(hi_i + __int_as_float(r2.y)));
        float w3 = __expf(leaky(hi_i + __int_as_float(r3.y)));
        acc = fmaf(w0, v0, acc); acc = fmaf(w1, v1, acc);
        acc = fmaf(w2, v2, acc); acc = fmaf(w3, v3, acc);
        s += (w0 + w1) + (w2 + w3);
    }
    for (; p < e; p++){
        int2 r = adj_n[p];
        float v = bf2f(hb[(size_t)r.x * 64 + lane]);
        float w = __expf(leaky(hi_i + __int_as_float(r.y)));
        acc = fmaf(w, v, acc); s += w;
    }
    out[(size_t)i * 128 + lane] = leaky(acc / s / (float)(cnt + 1));
}

// ---------------- edge branch: acc_ea (raw bf16 ea accumulation) ----------------
__global__ __launch_bounds__(256) void k_out_e(const unsigned short* __restrict__ eab,
        const float* __restrict__ he,
        const int* __restrict__ off_e, const int* __restrict__ deg_e,
        const int2* __restrict__ adj_e,
        float* __restrict__ acc_ea, int N){
    int lane = threadIdx.x & 63;
    int i = (blockIdx.x * 256 + threadIdx.x) >> 6;
    if (i >= N) return;
    float he_i = he[i];
    float s = 0.f, acc = 0.f;
    int cnt = deg_e[i];
    int p = off_e[i], e = p + cnt;
    for (; p + 4 <= e; p += 4){
        int2 r0 = adj_e[p], r1 = adj_e[p+1], r2 = adj_e[p+2], r3 = adj_e[p+3];
        float v0 = bf2f(eab[(size_t)r0.x * 64 + lane]);
        float v1 = bf2f(eab[(size_t)r1.x * 64 + lane]);
        float v2 = bf2f(eab[(size_t)r2.x * 64 + lane]);
        float v3 = bf2f(eab[(size_t)r3.x * 64 + lane]);
        float w0 = __expf(leaky(he_i + __int_as_float(r0.y)));
        float w1 = __expf(leaky(he_i + __int_as_float(r1.y)));
        float w2 = __expf(leaky(he_i + __int_as_float(r2.y)));
        float w3 = __expf(leaky(he_i + __int_as_float(r3.y)));
        acc = fmaf(w0, v0, acc); acc = fmaf(w1, v1, acc);
        acc = fmaf(w2, v2, acc); acc = fmaf(w3, v3, acc);
        s += (w0 + w1) + (w2 + w3);
    }
    for (; p < e; p++){
        int2 r = adj_e[p];
        float v = bf2f(eab[(size_t)r.x * 64 + lane]);
        float w = __expf(leaky(he_i + __int_as_float(r.y)));
        acc = fmaf(w, v, acc); s += w;
    }
    float val = (cnt > 0) ? (acc / s / (float)cnt) : 0.f;
    acc_ea[(size_t)i * 64 + lane] = val;
}

extern "C" void kernel_launch(void* const* d_in, const int* in_sizes, int n_in,
                              void* d_out, int out_size, void* d_ws, size_t ws_size,
                              hipStream_t stream){
    const float* x      = (const float*)d_in[0];
    const float* ea     = (const float*)d_in[1];
    const int*   idx    = (const int*)  d_in[2];
    const float* Wn     = (const float*)d_in[3];
    const float* We     = (const float*)d_in[4];
    const float* a_node = (const float*)d_in[5];
    const float* a_edge = (const float*)d_in[6];
    float* out = (float*)d_out;

    const int N = in_sizes[0] / 128;   // 50000
    const int E = in_sizes[1] / 64;    // 800000

    float* p = (float*)d_ws;
    float* h      = p; p += (size_t)N * 64;
    float* hi     = p; p += N;
    float* hj     = p; p += N;
    float* he     = p; p += N;
    float* ge     = p; p += E;
    float* acc_ea = p; p += (size_t)N * 64;
    unsigned short* hb  = (unsigned short*)p; p += (size_t)N * 32;   // bf16 h
    unsigned short* eab = (unsigned short*)p; p += (size_t)E * 32;   // bf16 ea
    int* deg_n = (int*)p; p += N;
    int* deg_o = (int*)p; p += N;
    int* deg_e = (int*)p; p += N;
    int* off_n = (int*)p; p += N;
    int* off_e = (int*)p; p += N;
    int* cur_n = (int*)p; p += N;
    int* cur_e = (int*)p; p += N;
    int2* adj_n = (int2*)p; p += (size_t)2 * E;
    int2* adj_e = (int2*)p; p += (size_t)4 * E;

    k_init<<<256, 256, 0, stream>>>(deg_n, deg_o, N);
    k_gemm64<128, false, true><<<(N + 63) / 64, 256, 0, stream>>>(x, Wn, h, hb, N, 64);
    k_scal<<<(N + 255) / 256, 256, 0, stream>>>(h, a_node, a_edge, hi, hj, he, N);
    k_ge<<<(E + 255) / 256, 256, 0, stream>>>(ea, We, a_edge, ge, eab, E);
    k_count<<<1024, 256, 0, stream>>>(idx, deg_n, deg_o, E, N);
    k_scan<<<2, 1024, 0, stream>>>(deg_n, deg_o, off_n, cur_n, off_e, cur_e, deg_e, N);
    k_fill<<<1024, 256, 0, stream>>>(idx, hj, ge, cur_n, cur_e, adj_n, adj_e, E, N);
    k_out_n<<<(N + 3) / 4, 256, 0, stream>>>(h, hb, hi, hj, off_n, deg_n, adj_n, out, N);
    k_out_e<<<(N + 3) / 4, 256, 0, stream>>>(eab, he, off_e, deg_e, adj_e, acc_ea, N);
    k_gemm64<64, true, false><<<(N + 63) / 64, 256, 0, stream>>>(acc_ea, We, out + 64, nullptr, N, 128);
}

// Round 6
// 699.829 us; speedup vs baseline: 1.2609x; 1.2609x over previous
//
#include <hip/hip_runtime.h>
#include <math.h>

#define NEG_SLOPE 0.05f

__device__ __forceinline__ float leaky(float x){ return x >= 0.f ? x : NEG_SLOPE * x; }

// bf16 helpers (RNE pack, truncated-float unpack)
__device__ __forceinline__ unsigned short f2bf(float f){
    unsigned u = __float_as_uint(f);
    unsigned r = u + 0x7FFFu + ((u >> 16) & 1u);
    return (unsigned short)(r >> 16);
}
__device__ __forceinline__ float bf2f(unsigned short us){
    return __uint_as_float((unsigned)us << 16);
}

// ---------------- K0: zero degree arrays + global offset counters ----------------
__global__ __launch_bounds__(256) void k_init(int* deg_n, int* deg_o, int* ctr, int N){
    int t = blockIdx.x * blockDim.x + threadIdx.x;
    if (t == 0){ ctr[0] = 0; ctr[1] = 0; }
    int stride = gridDim.x * blockDim.x;
    for (int i = t; i < N; i += stride){ deg_n[i] = 0; deg_o[i] = 0; }
}

// ---------------- tiled GEMM: C[M x 64] = A[M x K] @ B[64 x K]^T (+ optional bf16 copy) ----------------
template<int K, bool LEAKY, bool BF16OUT>
__global__ __launch_bounds__(256) void k_gemm64(const float* __restrict__ A, const float* __restrict__ B,
                                                float* __restrict__ C, unsigned short* __restrict__ Cb,
                                                int M, int ldC){
    __shared__ float As[K][68];
    __shared__ float Bs[K][68];
    const int m0 = blockIdx.x * 64;
    const int t = threadIdx.x;
    for (int i = t; i < 16 * K; i += 256){
        int d = i & 63, kq = i >> 6;
        float4 b = *(const float4*)&B[(size_t)d * K + kq * 4];
        Bs[kq*4+0][d] = b.x; Bs[kq*4+1][d] = b.y; Bs[kq*4+2][d] = b.z; Bs[kq*4+3][d] = b.w;
    }
    for (int i = t; i < 16 * K; i += 256){
        int r = i & 63, kq = i >> 6;
        int m = m0 + r;
        float4 a = make_float4(0.f, 0.f, 0.f, 0.f);
        if (m < M) a = *(const float4*)&A[(size_t)m * K + kq * 4];
        As[kq*4+0][r] = a.x; As[kq*4+1][r] = a.y; As[kq*4+2][r] = a.z; As[kq*4+3][r] = a.w;
    }
    __syncthreads();
    const int tx = t & 15, ty = t >> 4;
    float acc[4][4] = {};
    #pragma unroll 4
    for (int k = 0; k < K; k++){
        float4 a4 = *(const float4*)&As[k][ty * 4];
        float4 b4 = *(const float4*)&Bs[k][tx * 4];
        float av[4] = {a4.x, a4.y, a4.z, a4.w};
        float bv[4] = {b4.x, b4.y, b4.z, b4.w};
        #pragma unroll
        for (int r = 0; r < 4; r++)
            #pragma unroll
            for (int c = 0; c < 4; c++)
                acc[r][c] = fmaf(av[r], bv[c], acc[r][c]);
    }
    #pragma unroll
    for (int r = 0; r < 4; r++){
        int m = m0 + ty * 4 + r;
        if (m < M){
            float4 o;
            o.x = LEAKY ? leaky(acc[r][0]) : acc[r][0];
            o.y = LEAKY ? leaky(acc[r][1]) : acc[r][1];
            o.z = LEAKY ? leaky(acc[r][2]) : acc[r][2];
            o.w = LEAKY ? leaky(acc[r][3]) : acc[r][3];
            *(float4*)&C[(size_t)m * ldC + tx * 4] = o;
            if (BF16OUT){
                uint2 u;
                u.x = (unsigned)f2bf(o.x) | ((unsigned)f2bf(o.y) << 16);
                u.y = (unsigned)f2bf(o.z) | ((unsigned)f2bf(o.w) << 16);
                *(uint2*)&Cb[(size_t)m * 64 + tx * 4] = u;
            }
        }
    }
}

// ---------------- per-node scalars hi/hj/he ----------------
__global__ __launch_bounds__(256) void k_scal(const float* __restrict__ h,
        const float* __restrict__ a_node, const float* __restrict__ a_edge,
        float* __restrict__ hi, float* __restrict__ hj, float* __restrict__ he, int N){
    int i = blockIdx.x * 256 + threadIdx.x;
    if (i >= N) return;
    const float4* hr = (const float4*)(h + (size_t)i * 64);
    const float4* a1 = (const float4*)a_node;
    const float4* a2 = (const float4*)(a_node + 64);
    const float4* a3 = (const float4*)a_edge;
    float s1 = 0.f, s2 = 0.f, s3 = 0.f;
    #pragma unroll
    for (int q = 0; q < 16; q++){
        float4 v = hr[q], w1 = a1[q], w2 = a2[q], w3 = a3[q];
        s1 += v.x*w1.x + v.y*w1.y + v.z*w1.z + v.w*w1.w;
        s2 += v.x*w2.x + v.y*w2.y + v.z*w2.z + v.w*w2.w;
        s3 += v.x*w3.x + v.y*w3.y + v.z*w3.z + v.w*w3.w;
    }
    hi[i] = s1; hj[i] = s2; he[i] = s3;
}

// ---------------- ge[k] = ea[k].(We^T a2); also emit bf16 copy of ea ----------------
__global__ __launch_bounds__(256) void k_ge(const float* __restrict__ ea,
        const float* __restrict__ We, const float* __restrict__ a_edge,
        float* __restrict__ ge, unsigned short* __restrict__ eab, int E){
    __shared__ float v[64];
    if (threadIdx.x < 64){
        float s = 0.f;
        for (int d = 0; d < 64; d++) s = fmaf(We[d * 64 + threadIdx.x], a_edge[64 + d], s);
        v[threadIdx.x] = s;
    }
    __syncthreads();
    int k = blockIdx.x * 256 + threadIdx.x;
    if (k >= E) return;
    const float4* row = (const float4*)(ea + (size_t)k * 64);
    uint2* brow = (uint2*)(eab + (size_t)k * 64);
    float s = 0.f;
    #pragma unroll
    for (int q = 0; q < 16; q++){
        float4 r = row[q];
        s = fmaf(r.x, v[4*q+0], s);
        s = fmaf(r.y, v[4*q+1], s);
        s = fmaf(r.z, v[4*q+2], s);
        s = fmaf(r.w, v[4*q+3], s);
        uint2 u;
        u.x = (unsigned)f2bf(r.x) | ((unsigned)f2bf(r.y) << 16);
        u.y = (unsigned)f2bf(r.z) | ((unsigned)f2bf(r.w) << 16);
        brow[q] = u;
    }
    ge[k] = s;
}

// ---------------- XCD-partitioned degree count (2 atomics/edge) ----------------
__global__ __launch_bounds__(256) void k_count(const int* __restrict__ idx,
        int* __restrict__ deg_n, int* __restrict__ deg_o, int E, int N){
    int g = blockIdx.x & 7;
    int lo = (int)(((long long)g * N) >> 3), hi = (int)(((long long)(g + 1) * N) >> 3);
    int nblk = gridDim.x >> 3;
    int start = ((blockIdx.x >> 3) * 256) + threadIdx.x;
    int stride = nblk * 256;
    for (int k = start; k < E; k += stride){
        int i0 = idx[k], i1 = idx[E + k];
        if (i0 >= lo && i0 < hi) atomicAdd(&deg_n[i0], 1);
        if (i1 >= lo && i1 < hi) atomicAdd(&deg_o[i1], 1);
    }
}

// ---------------- parallel offset assignment: wave shfl-scan + one atomic per wave ----------------
// Adjacency ranges need only be DISJOINT, not ordered -> no global prefix scan needed.
__global__ __launch_bounds__(256) void k_off(const int* __restrict__ deg_n, const int* __restrict__ deg_o,
        int* __restrict__ deg_e,
        int* __restrict__ off_n, int* __restrict__ cur_n,
        int* __restrict__ off_e, int* __restrict__ cur_e,
        int* __restrict__ ctr, int N){
    int i = blockIdx.x * 256 + threadIdx.x;
    int lane = threadIdx.x & 63;
    int dn = 0, de = 0;
    if (i < N){
        dn = deg_n[i];
        de = dn + deg_o[i];
    }
    int pn = dn, pe = de;   // inclusive wave scan
    #pragma unroll
    for (int d = 1; d < 64; d <<= 1){
        int on = __shfl_up(pn, d), oe = __shfl_up(pe, d);
        if (lane >= d){ pn += on; pe += oe; }
    }
    int base_n = 0, base_e = 0;
    if (lane == 63){
        base_n = atomicAdd(&ctr[0], pn);
        base_e = atomicAdd(&ctr[1], pe);
    }
    base_n = __shfl(base_n, 63);
    base_e = __shfl(base_e, 63);
    if (i < N){
        int on = base_n + pn - dn;   // exclusive within wave
        int oe = base_e + pe - de;
        off_n[i] = on; cur_n[i] = on;
        off_e[i] = oe; cur_e[i] = oe;
        deg_e[i] = de;
    }
}

// ---------------- XCD-partitioned fill; records carry the attention scalar ----------------
__global__ __launch_bounds__(256) void k_fill(const int* __restrict__ idx,
        const float* __restrict__ hj, const float* __restrict__ ge,
        int* __restrict__ cur_n, int* __restrict__ cur_e,
        int2* __restrict__ adj_n, int2* __restrict__ adj_e, int E, int N){
    int g = blockIdx.x & 7;
    int lo = (int)(((long long)g * N) >> 3), hi = (int)(((long long)(g + 1) * N) >> 3);
    int nblk = gridDim.x >> 3;
    int start = ((blockIdx.x >> 3) * 256) + threadIdx.x;
    int stride = nblk * 256;
    for (int k = start; k < E; k += stride){
        int i0 = idx[k], i1 = idx[E + k];
        bool t0 = (i0 >= lo && i0 < hi), t1 = (i1 >= lo && i1 < hi);
        if (t0 | t1){
            int gb = __float_as_int(ge[k]);
            if (t0){
                adj_n[atomicAdd(&cur_n[i0], 1)] = make_int2(i1, __float_as_int(hj[i1]));
                adj_e[atomicAdd(&cur_e[i0], 1)] = make_int2(k, gb);
            }
            if (t1) adj_e[atomicAdd(&cur_e[i1], 1)] = make_int2(k, gb);
        }
    }
}

// ---------------- node branch: out[:, :64] (direct exp, bf16 gathers) ----------------
__global__ __launch_bounds__(256) void k_out_n(const float* __restrict__ h,
        const unsigned short* __restrict__ hb,
        const float* __restrict__ hi, const float* __restrict__ hj,
        const int* __restrict__ off_n, const int* __restrict__ deg_n,
        const int2* __restrict__ adj_n,
        float* __restrict__ out, int N){
    int lane = threadIdx.x & 63;
    int i = (blockIdx.x * 256 + threadIdx.x) >> 6;
    if (i >= N) return;
    float hi_i = hi[i];
    float wself = __expf(leaky(hi_i + hj[i]));
    float s = wself;
    float acc = wself * h[(size_t)i * 64 + lane];
    int cnt = deg_n[i];
    int p = off_n[i], e = p + cnt;
    for (; p + 4 <= e; p += 4){
        int2 r0 = adj_n[p], r1 = adj_n[p+1], r2 = adj_n[p+2], r3 = adj_n[p+3];
        float v0 = bf2f(hb[(size_t)r0.x * 64 + lane]);
        float v1 = bf2f(hb[(size_t)r1.x * 64 + lane]);
        float v2 = bf2f(hb[(size_t)r2.x * 64 + lane]);
        float v3 = bf2f(hb[(size_t)r3.x * 64 + lane]);
        float w0 = __expf(leaky(hi_i + __int_as_float(r0.y)));
        float w1 = __expf(leaky(hi_i + __int_as_float(r1.y)));
        float w2 = __expf(leaky(hi_i + __int_as_float(r2.y)));
        float w3 = __expf(leaky(hi_i + __int_as_float(r3.y)));
        acc = fmaf(w0, v0, acc); acc = fmaf(w1, v1, acc);
        acc = fmaf(w2, v2, acc); acc = fmaf(w3, v3, acc);
        s += (w0 + w1) + (w2 + w3);
    }
    for (; p < e; p++){
        int2 r = adj_n[p];
        float v = bf2f(hb[(size_t)r.x * 64 + lane]);
        float w = __expf(leaky(hi_i + __int_as_float(r.y)));
        acc = fmaf(w, v, acc); s += w;
    }
    out[(size_t)i * 128 + lane] = leaky(acc / s / (float)(cnt + 1));
}

// ---------------- edge branch: acc_ea (raw bf16 ea accumulation) ----------------
__global__ __launch_bounds__(256) void k_out_e(const unsigned short* __restrict__ eab,
        const float* __restrict__ he,
        const int* __restrict__ off_e, const int* __restrict__ deg_e,
        const int2* __restrict__ adj_e,
        float* __restrict__ acc_ea, int N){
    int lane = threadIdx.x & 63;
    int i = (blockIdx.x * 256 + threadIdx.x) >> 6;
    if (i >= N) return;
    float he_i = he[i];
    float s = 0.f, acc = 0.f;
    int cnt = deg_e[i];
    int p = off_e[i], e = p + cnt;
    for (; p + 4 <= e; p += 4){
        int2 r0 = adj_e[p], r1 = adj_e[p+1], r2 = adj_e[p+2], r3 = adj_e[p+3];
        float v0 = bf2f(eab[(size_t)r0.x * 64 + lane]);
        float v1 = bf2f(eab[(size_t)r1.x * 64 + lane]);
        float v2 = bf2f(eab[(size_t)r2.x * 64 + lane]);
        float v3 = bf2f(eab[(size_t)r3.x * 64 + lane]);
        float w0 = __expf(leaky(he_i + __int_as_float(r0.y)));
        float w1 = __expf(leaky(he_i + __int_as_float(r1.y)));
        float w2 = __expf(leaky(he_i + __int_as_float(r2.y)));
        float w3 = __expf(leaky(he_i + __int_as_float(r3.y)));
        acc = fmaf(w0, v0, acc); acc = fmaf(w1, v1, acc);
        acc = fmaf(w2, v2, acc); acc = fmaf(w3, v3, acc);
        s += (w0 + w1) + (w2 + w3);
    }
    for (; p < e; p++){
        int2 r = adj_e[p];
        float v = bf2f(eab[(size_t)r.x * 64 + lane]);
        float w = __expf(leaky(he_i + __int_as_float(r.y)));
        acc = fmaf(w, v, acc); s += w;
    }
    float val = (cnt > 0) ? (acc / s / (float)cnt) : 0.f;
    acc_ea[(size_t)i * 64 + lane] = val;
}

extern "C" void kernel_launch(void* const* d_in, const int* in_sizes, int n_in,
                              void* d_out, int out_size, void* d_ws, size_t ws_size,
                              hipStream_t stream){
    const float* x      = (const float*)d_in[0];
    const float* ea     = (const float*)d_in[1];
    const int*   idx    = (const int*)  d_in[2];
    const float* Wn     = (const float*)d_in[3];
    const float* We     = (const float*)d_in[4];
    const float* a_node = (const float*)d_in[5];
    const float* a_edge = (const float*)d_in[6];
    float* out = (float*)d_out;

    const int N = in_sizes[0] / 128;   // 50000
    const int E = in_sizes[1] / 64;    // 800000

    float* p = (float*)d_ws;
    float* h      = p; p += (size_t)N * 64;
    float* hi     = p; p += N;
    float* hj     = p; p += N;
    float* he     = p; p += N;
    float* ge     = p; p += E;
    float* acc_ea = p; p += (size_t)N * 64;
    unsigned short* hb  = (unsigned short*)p; p += (size_t)N * 32;   // bf16 h
    unsigned short* eab = (unsigned short*)p; p += (size_t)E * 32;   // bf16 ea
    int* deg_n = (int*)p; p += N;
    int* deg_o = (int*)p; p += N;
    int* deg_e = (int*)p; p += N;
    int* off_n = (int*)p; p += N;
    int* off_e = (int*)p; p += N;
    int* cur_n = (int*)p; p += N;
    int* cur_e = (int*)p; p += N;
    int* ctr   = (int*)p; p += 2;
    int2* adj_n = (int2*)p; p += (size_t)2 * E;
    int2* adj_e = (int2*)p; p += (size_t)4 * E;

    k_init<<<256, 256, 0, stream>>>(deg_n, deg_o, ctr, N);
    k_gemm64<128, false, true><<<(N + 63) / 64, 256, 0, stream>>>(x, Wn, h, hb, N, 64);
    k_scal<<<(N + 255) / 256, 256, 0, stream>>>(h, a_node, a_edge, hi, hj, he, N);
    k_ge<<<(E + 255) / 256, 256, 0, stream>>>(ea, We, a_edge, ge, eab, E);
    k_count<<<1024, 256, 0, stream>>>(idx, deg_n, deg_o, E, N);
    k_off<<<(N + 255) / 256, 256, 0, stream>>>(deg_n, deg_o, deg_e, off_n, cur_n, off_e, cur_e, ctr, N);
    k_fill<<<1024, 256, 0, stream>>>(idx, hj, ge, cur_n, cur_e, adj_n, adj_e, E, N);
    k_out_n<<<(N + 3) / 4, 256, 0, stream>>>(h, hb, hi, hj, off_n, deg_n, adj_n, out, N);
    k_out_e<<<(N + 3) / 4, 256, 0, stream>>>(eab, he, off_e, deg_e, adj_e, acc_ea, N);
    k_gemm64<64, true, false><<<(N + 63) / 64, 256, 0, stream>>>(acc_ea, We, out + 64, nullptr, N, 128);
}